// Round 1
// baseline (186.336 us; speedup 1.0000x reference)
//
#include <hip/hip_runtime.h>
#include <hip/hip_bf16.h>
#include <math.h>

#define NPTS 524288
#define HDIM 256
#define NBLK (NPTS / 256)
#define STEPS 100

// Constants matching the reference (computed in double, rounded once to float)
constexpr float DXF      = (float)(20.0 / (NPTS - 1));          // (X_MAX-X_MIN)/(N-1)
constexpr float DTF      = 0.01f;
constexpr float SQRT2DT  = 0.14142135623730951f;                 // np.float32(sqrt(2*DT))
constexpr float TWO_LOG2E = 2.8853900817779268f;                 // 2*log2(e)

// ---------------------------------------------------------------------------
// Kernel 1: per-point NN eval + analytic second derivative + h_psi + partial
// reductions. One thread per grid point, loop over H=256 hidden units.
// Weights are wave-uniform -> compiler should scalarize (s_load).
// ---------------------------------------------------------------------------
__global__ __launch_bounds__(256) void qpe_main(
    const float* __restrict__ x,  const float* __restrict__ V,
    const float* __restrict__ W1, const float* __restrict__ b1,
    const float* __restrict__ W2, const float* __restrict__ b2,
    float* __restrict__ out,      float* __restrict__ nd_arr,
    float* __restrict__ pdens,    float* __restrict__ pnd)
{
    const int i = blockIdx.x * 256 + threadIdx.x;
    const float xi = x[i];
    const float Vi = V[i];

    float psi0 = b2[0];
    float psi1 = b2[1];
    float ta0 = 0.0f, ta1 = 0.0f;   // accumulates t_psi = K_TERM*lap directly

    #pragma unroll 8
    for (int h = 0; h < HDIM; ++h) {
        const float w1  = W1[h];
        const float u   = fmaf(xi, w1, b1[h]);
        // tanh(u) = 1 - 2/(exp(2u)+1), via exp2
        const float e   = __builtin_amdgcn_exp2f(u * TWO_LOG2E);
        const float r   = __builtin_amdgcn_rcpf(e + 1.0f);
        const float t   = fmaf(-2.0f, r, 1.0f);
        const float omt2 = fmaf(-t, t, 1.0f);        // 1 - t^2
        const float gg  = (t * omt2) * (w1 * w1);    // t(1-t^2) * W1^2
        const float w20 = W2[2*h];
        const float w21 = W2[2*h + 1];
        psi0 = fmaf(w20, t,  psi0);
        psi1 = fmaf(w21, t,  psi1);
        ta0  = fmaf(w20, gg, ta0);
        ta1  = fmaf(w21, gg, ta1);
    }

    const float hp0 = fmaf(Vi, psi0, ta0);   // h_psi = t_psi + V*psi
    const float hp1 = fmaf(Vi, psi1, ta1);

    *reinterpret_cast<float2*>(&out[2*i]) = make_float2(hp0, hp1);

    const float nd = fmaf(psi0, psi0, psi1 * psi1);   // norm_densities
    nd_arr[i] = nd;

    float dens = fmaf(psi0, hp0, psi1 * hp1);         // densities
    float ndr  = nd;

    // wave64 reduction
    for (int off = 32; off; off >>= 1) {
        dens += __shfl_down(dens, off);
        ndr  += __shfl_down(ndr, off);
    }
    __shared__ float sd[4], sn[4];
    const int lane = threadIdx.x & 63;
    const int wid  = threadIdx.x >> 6;
    if (lane == 0) { sd[wid] = dens; sn[wid] = ndr; }
    __syncthreads();
    if (threadIdx.x == 0) {
        pdens[blockIdx.x] = sd[0] + sd[1] + sd[2] + sd[3];
        pnd[blockIdx.x]   = sn[0] + sn[1] + sn[2] + sn[3];
    }
}

// ---------------------------------------------------------------------------
// Kernel 2: reduce 2048 block partials -> energy (out[2N]) and denom (ws)
// ---------------------------------------------------------------------------
__global__ __launch_bounds__(1024) void qpe_reduce(
    const float* __restrict__ pdens, const float* __restrict__ pnd,
    float* __restrict__ energy_out,  float* __restrict__ denom_out)
{
    const int tid = threadIdx.x;
    float d = pdens[tid] + pdens[tid + 1024];
    float n = pnd[tid]   + pnd[tid + 1024];
    for (int off = 32; off; off >>= 1) {
        d += __shfl_down(d, off);
        n += __shfl_down(n, off);
    }
    __shared__ float sd[16], sn[16];
    const int lane = tid & 63;
    const int wid  = tid >> 6;
    if (lane == 0) { sd[wid] = d; sn[wid] = n; }
    __syncthreads();
    if (tid == 0) {
        float Sd = 0.0f, Sn = 0.0f;
        #pragma unroll
        for (int w = 0; w < 16; ++w) { Sd += sd[w]; Sn += sn[w]; }
        const float denom = Sn * DXF + 1e-8f;
        energy_out[0] = (Sd * DXF) / denom;
        denom_out[0]  = denom;
    }
}

// ---------------------------------------------------------------------------
// Kernel 3: 100-step sequential Langevin walk (data-dependent -> serial).
// Single thread; two parallel L2-resident loads + 2 logs per step.
// ---------------------------------------------------------------------------
__global__ void qpe_scan(
    const float* __restrict__ x,       const float* __restrict__ nd_arr,
    const float* __restrict__ denom_p, const float* __restrict__ noise,
    const int*  __restrict__ init_idx, float* __restrict__ xc_out)
{
    if (threadIdx.x != 0 || blockIdx.x != 0) return;
    const float denom = denom_p[0];
    int c = init_idx[0];
    for (int t = 0; t < STEPS; ++t) {
        float s = 0.0f;
        if (c > 0 && c < NPTS - 1) {
            // prob = nd/denom; log_prob = log(prob + 1e-10); central difference
            const float lp = logf(__fdiv_rn(nd_arr[c + 1], denom) + 1e-10f);
            const float lm = logf(__fdiv_rn(nd_arr[c - 1], denom) + 1e-10f);
            s = __fdiv_rn(__fsub_rn(lp, lm), 2.0f * DXF);
        }
        // shift = int32((s*DT + z*sqrt2dt)/DX), truncation toward zero
        const float a = __fadd_rn(__fmul_rn(s, DTF), __fmul_rn(noise[t], SQRT2DT));
        const int shift = (int)__fdiv_rn(a, DXF);
        c += shift;
        c = c < 0 ? 0 : (c > NPTS - 1 ? NPTS - 1 : c);
    }
    xc_out[0] = x[c];
}

// ---------------------------------------------------------------------------
extern "C" void kernel_launch(void* const* d_in, const int* in_sizes, int n_in,
                              void* d_out, int out_size, void* d_ws, size_t ws_size,
                              hipStream_t stream) {
    const float* x        = (const float*)d_in[0];
    const float* V        = (const float*)d_in[1];
    const float* W1       = (const float*)d_in[2];
    const float* b1       = (const float*)d_in[3];
    const float* W2       = (const float*)d_in[4];
    const float* b2       = (const float*)d_in[5];
    const float* noise    = (const float*)d_in[6];
    const int*   init_idx = (const int*)d_in[7];

    float* out = (float*)d_out;
    float* ws  = (float*)d_ws;

    float* nd_arr = ws;                    // N floats
    float* pdens  = ws + NPTS;             // 2048 floats
    float* pnd    = ws + NPTS + 2048;      // 2048 floats
    float* denom  = ws + NPTS + 4096;      // 1 float

    qpe_main<<<NBLK, 256, 0, stream>>>(x, V, W1, b1, W2, b2, out, nd_arr, pdens, pnd);
    qpe_reduce<<<1, 1024, 0, stream>>>(pdens, pnd, out + 2*NPTS, denom);
    qpe_scan<<<1, 64, 0, stream>>>(x, nd_arr, denom, noise, init_idx, out + 2*NPTS + 1);
}

// Round 2
// 138.151 us; speedup vs baseline: 1.3488x; 1.3488x over previous
//
#include <hip/hip_runtime.h>
#include <hip/hip_bf16.h>
#include <math.h>

#define NPTS 524288
#define HDIM 256
#define NBLK (NPTS / 256)
#define STEPS 100

// Constants matching the reference (computed in double, rounded once to float)
constexpr float DXF       = (float)(20.0 / (NPTS - 1));
constexpr float TWODXF    = (float)(2.0 * (20.0 / (NPTS - 1)));
constexpr float DTF       = 0.01f;
constexpr float SQRT2DT   = 0.14142135623730951f;   // np.float32(sqrt(2*DT))
constexpr float TWO_LOG2E = 2.8853900817779268f;    // 2*log2(e)

typedef float v2f __attribute__((ext_vector_type(2)));

static __device__ __forceinline__ v2f vfma(v2f a, v2f b, v2f c) {
#if __has_builtin(__builtin_elementwise_fma)
    return __builtin_elementwise_fma(a, b, c);
#else
    v2f r; r.x = fmaf(a.x, b.x, c.x); r.y = fmaf(a.y, b.y, c.y); return r;
#endif
}

// ---------------------------------------------------------------------------
// Kernel 0: fuse weight constants so the hot loop sheds 3 VALU ops per h.
// wk layout (256 floats each): w1k | b1k | w20 | w21 | wg0 | wg1
//   w1k = W1*2log2e, b1k = b1*2log2e, wg{0,1} = W2[:,{0,1}]*W1^2
// ---------------------------------------------------------------------------
__global__ void qpe_prep(const float* __restrict__ W1, const float* __restrict__ b1,
                         const float* __restrict__ W2, float* __restrict__ wk)
{
    const int h = threadIdx.x;
    const float w1  = W1[h];
    const float w20 = W2[2*h];
    const float w21 = W2[2*h + 1];
    const float w1s = w1 * w1;
    wk[h]        = w1 * TWO_LOG2E;
    wk[256 + h]  = b1[h] * TWO_LOG2E;
    wk[512 + h]  = w20;
    wk[768 + h]  = w21;
    wk[1024 + h] = w20 * w1s;
    wk[1280 + h] = w21 * w1s;
}

// ---------------------------------------------------------------------------
// Kernel 1: per-point NN eval + analytic 2nd derivative, packed fp32 over
// h-pairs (v_pk_fma_f32 path). Writes h_psi, lp = log(nd), block partials.
// tanh(u) = 1 - 2/(exp2(u*2log2e)+1);  t_psi = sum W2*W1^2*(t - t^3)
// ---------------------------------------------------------------------------
__global__ __launch_bounds__(256) void qpe_main(
    const float* __restrict__ x,  const float* __restrict__ V,
    const float* __restrict__ wk, const float* __restrict__ b2,
    float* __restrict__ out,      float* __restrict__ lp_arr,
    float* __restrict__ pdens,    float* __restrict__ pnd)
{
    const int i = blockIdx.x * 256 + threadIdx.x;
    const float xi = x[i];
    const float Vi = V[i];

    const v2f* __restrict__ w1k2 = (const v2f*)(wk);
    const v2f* __restrict__ b1k2 = (const v2f*)(wk + 256);
    const v2f* __restrict__ w202 = (const v2f*)(wk + 512);
    const v2f* __restrict__ w212 = (const v2f*)(wk + 768);
    const v2f* __restrict__ wg02 = (const v2f*)(wk + 1024);
    const v2f* __restrict__ wg12 = (const v2f*)(wk + 1280);

    const v2f x2   = {xi, xi};
    const v2f one2 = {1.0f, 1.0f};
    const v2f m2   = {-2.0f, -2.0f};
    v2f p0 = {0.f, 0.f}, p1 = {0.f, 0.f};   // psi accumulators (even/odd h)
    v2f a0 = {0.f, 0.f}, a1 = {0.f, 0.f};   // t_psi accumulators

    #pragma unroll 8
    for (int j = 0; j < HDIM / 2; ++j) {
        const v2f u = vfma(x2, w1k2[j], b1k2[j]);
        v2f e; e.x = __builtin_amdgcn_exp2f(u.x); e.y = __builtin_amdgcn_exp2f(u.y);
        const v2f dd = e + one2;
        v2f r; r.x = __builtin_amdgcn_rcpf(dd.x); r.y = __builtin_amdgcn_rcpf(dd.y);
        const v2f t  = vfma(m2, r, one2);          // tanh
        const v2f o  = vfma(-t, t, one2);          // 1 - t^2
        const v2f g  = t * o;                      // t(1-t^2)
        p0 = vfma(w202[j], t, p0);
        p1 = vfma(w212[j], t, p1);
        a0 = vfma(wg02[j], g, a0);
        a1 = vfma(wg12[j], g, a1);
    }

    const float psi0 = p0.x + p0.y + b2[0];
    const float psi1 = p1.x + p1.y + b2[1];
    const float ta0  = a0.x + a0.y;
    const float ta1  = a1.x + a1.y;

    const float hp0 = fmaf(Vi, psi0, ta0);   // h_psi = K*lap + V*psi
    const float hp1 = fmaf(Vi, psi1, ta1);
    *reinterpret_cast<float2*>(&out[2*i]) = make_float2(hp0, hp1);

    const float nd = fmaf(psi0, psi0, psi1 * psi1);
    lp_arr[i] = logf(nd);                    // denom cancels in central diff

    float dens = fmaf(psi0, hp0, psi1 * hp1);
    float ndr  = nd;
    for (int off = 32; off; off >>= 1) {
        dens += __shfl_down(dens, off);
        ndr  += __shfl_down(ndr, off);
    }
    __shared__ float sd[4], sn[4];
    const int lane = threadIdx.x & 63;
    const int wid  = threadIdx.x >> 6;
    if (lane == 0) { sd[wid] = dens; sn[wid] = ndr; }
    __syncthreads();
    if (threadIdx.x == 0) {
        pdens[blockIdx.x] = sd[0] + sd[1] + sd[2] + sd[3];
        pnd[blockIdx.x]   = sn[0] + sn[1] + sn[2] + sn[3];
    }
}

// ---------------------------------------------------------------------------
// Kernel 2 (fused tail), one block of 256:
//   wave0 lane0 : 100-step serial Langevin walk on lp array
//   wave1       : reduce 2048+2048 block partials -> energy
//   waves2-3    : prefetch +-64Ki lp window around init_idx into local L2/L1
// No __syncthreads: the three roles are independent.
// ---------------------------------------------------------------------------
__global__ __launch_bounds__(256) void qpe_tail(
    const float* __restrict__ x,     const float* __restrict__ lp,
    const float* __restrict__ pdens, const float* __restrict__ pnd,
    const float* __restrict__ noise, const int* __restrict__ init_idx,
    float* __restrict__ out,         float* __restrict__ dummy)
{
    const int tid = threadIdx.x;
    if (tid < 64) {
        if (tid == 0) {
            int c = init_idx[0];
            for (int t = 0; t < STEPS; ++t) {
                float s = 0.0f;
                if (c > 0 && c < NPTS - 1) {
                    const float lpp = lp[c + 1];
                    const float lpm = lp[c - 1];
                    s = __fdiv_rn(__fsub_rn(lpp, lpm), TWODXF);
                }
                const float a = __fadd_rn(__fmul_rn(s, DTF),
                                          __fmul_rn(noise[t], SQRT2DT));
                const int shift = (int)__fdiv_rn(a, DXF);
                c += shift;
                c = c < 0 ? 0 : (c > NPTS - 1 ? NPTS - 1 : c);
            }
            out[2 * NPTS + 1] = x[c];
        }
    } else if (tid < 128) {
        const int l = tid - 64;
        float d = 0.f, n = 0.f;
        #pragma unroll 8
        for (int k = 0; k < 32; ++k) {
            d += pdens[l + 64 * k];
            n += pnd[l + 64 * k];
        }
        for (int off = 32; off; off >>= 1) {
            d += __shfl_down(d, off);
            n += __shfl_down(n, off);
        }
        if (l == 0)
            out[2 * NPTS] = __fdiv_rn(d * DXF, fmaf(n, DXF, 1e-8f));
    } else {
        // prefetch lp window into this XCD's L2 (and this CU's L1)
        int c0 = init_idx[0];
        int start = c0 - 65536;
        if (start < 0) start = 0;
        if (start > NPTS - 131072) start = NPTS - 131072;
        start &= ~3;
        const float4* __restrict__ src = (const float4*)(lp + start);
        const int l = tid - 128;
        float acc = 0.f;
        #pragma unroll 4
        for (int k = 0; k < 256; ++k) {
            const float4 v = src[l + 128 * k];
            acc += v.x + v.y + v.z + v.w;
        }
        if (acc == 123456.789f) dummy[0] = acc;   // keep loads alive
    }
}

// ---------------------------------------------------------------------------
extern "C" void kernel_launch(void* const* d_in, const int* in_sizes, int n_in,
                              void* d_out, int out_size, void* d_ws, size_t ws_size,
                              hipStream_t stream) {
    const float* x        = (const float*)d_in[0];
    const float* V        = (const float*)d_in[1];
    const float* W1       = (const float*)d_in[2];
    const float* b1       = (const float*)d_in[3];
    const float* W2       = (const float*)d_in[4];
    const float* b2       = (const float*)d_in[5];
    const float* noise    = (const float*)d_in[6];
    const int*   init_idx = (const int*)d_in[7];

    float* out = (float*)d_out;
    float* ws  = (float*)d_ws;

    float* lp_arr = ws;                         // N floats
    float* pdens  = ws + NPTS;                  // 2048
    float* pnd    = ws + NPTS + 2048;           // 2048
    float* wk     = ws + NPTS + 4096;           // 1536
    float* dummy  = ws + NPTS + 4096 + 1536;    // 1

    qpe_prep<<<1, 256, 0, stream>>>(W1, b1, W2, wk);
    qpe_main<<<NBLK, 256, 0, stream>>>(x, V, wk, b2, out, lp_arr, pdens, pnd);
    qpe_tail<<<1, 256, 0, stream>>>(x, lp_arr, pdens, pnd, noise, init_idx,
                                    out, dummy);
}